// Round 1
// baseline (296.297 us; speedup 1.0000x reference)
//
#include <hip/hip_runtime.h>
#include <hip/hip_bf16.h>

// Problem constants (from reference)
#define BB   16
#define NS   1024
#define NT   4096
#define CIN  256
#define CSK  64
#define HD   256           // hidden dim / output cols
#define K1   (CIN + CSK)   // 320
#define MTOT (BB * NT)     // 65536

typedef __attribute__((ext_vector_type(4))) float f32x4;
typedef __attribute__((ext_vector_type(8))) __bf16 bf16x8;
typedef __attribute__((ext_vector_type(4))) unsigned short ushort4v;

// ws layout (bytes)
#define IDX_OFF 0u                    // int[MTOT*3]      = 786432
#define WGT_OFF 786432u               // float[MTOT*3]    = 786432
#define W1F_OFF 1572864u              // bf16[320*256]    = 163840
#define W2F_OFF 1736704u              // bf16[256*256]    = 131072
#define HIN_OFF 2097152u              // bf16[MTOT*320]   = 41943040
#define H1_OFF  44040192u             // bf16[MTOT*256]   = 33554432
// total ~77.6 MB

static __device__ __forceinline__ unsigned short f2bf(float f) {
    union { float f; unsigned int u; } v; v.f = f;
    unsigned int r = (v.u + 0x7FFFu + ((v.u >> 16) & 1u)) >> 16;
    return (unsigned short)r;
}

// ---------------- kNN (K=3) over per-cloud 1024 points ----------------
__global__ __launch_bounds__(256) void knn_kernel(
    const float* __restrict__ pos, const float* __restrict__ pos_skip,
    int* __restrict__ idx_out, float* __restrict__ wgt_out)
{
    __shared__ float sp[NS * 3];
    const int blocks_per_cloud = NT / 256;       // 16
    const int cloud = blockIdx.x / blocks_per_cloud;
    const int q = cloud * NT + (blockIdx.x % blocks_per_cloud) * 256 + threadIdx.x;
    const float* pc = pos + (size_t)cloud * NS * 3;
    for (int i = threadIdx.x; i < NS * 3; i += 256) sp[i] = pc[i];
    __syncthreads();

    const float qx = pos_skip[q * 3 + 0];
    const float qy = pos_skip[q * 3 + 1];
    const float qz = pos_skip[q * 3 + 2];

    float b0 = 1e30f, b1 = 1e30f, b2 = 1e30f;
    int   i0 = 0, i1 = 0, i2 = 0;
    #pragma unroll 4
    for (int s = 0; s < NS; ++s) {
        float dx = qx - sp[s * 3 + 0];
        float dy = qy - sp[s * 3 + 1];
        float dz = qz - sp[s * 3 + 2];
        float d = dx * dx + dy * dy + dz * dz;
        if (d < b2) {
            if (d < b1) {
                if (d < b0) { b2 = b1; i2 = i1; b1 = b0; i1 = i0; b0 = d; i0 = s; }
                else        { b2 = b1; i2 = i1; b1 = d;  i1 = s; }
            } else          { b2 = d;  i2 = s; }
        }
    }
    float w0 = 1.f / fmaxf(b0, 1e-16f);
    float w1 = 1.f / fmaxf(b1, 1e-16f);
    float w2 = 1.f / fmaxf(b2, 1e-16f);
    float inv = 1.f / (w0 + w1 + w2);
    idx_out[q * 3 + 0] = cloud * NS + i0;
    idx_out[q * 3 + 1] = cloud * NS + i1;
    idx_out[q * 3 + 2] = cloud * NS + i2;
    wgt_out[q * 3 + 0] = w0 * inv;
    wgt_out[q * 3 + 1] = w1 * inv;
    wgt_out[q * 3 + 2] = w2 * inv;
}

// ------- interpolate + concat skip -> hin bf16 [MTOT, 320], row-major -------
__global__ __launch_bounds__(256) void interp_kernel(
    const float* __restrict__ x, const float* __restrict__ x_skip,
    const int* __restrict__ idx, const float* __restrict__ wgt,
    unsigned short* __restrict__ hin)
{
    const int g = blockIdx.x * 4 + (threadIdx.x >> 6);
    const int lane = threadIdx.x & 63;
    const int i0 = idx[g * 3 + 0], i1 = idx[g * 3 + 1], i2 = idx[g * 3 + 2];
    const float w0 = wgt[g * 3 + 0], w1 = wgt[g * 3 + 1], w2 = wgt[g * 3 + 2];
    const f32x4* r0 = (const f32x4*)(x + (size_t)i0 * CIN);
    const f32x4* r1 = (const f32x4*)(x + (size_t)i1 * CIN);
    const f32x4* r2 = (const f32x4*)(x + (size_t)i2 * CIN);
    f32x4 a = r0[lane], b = r1[lane], c = r2[lane];
    f32x4 y = a * w0 + b * w1 + c * w2;
    ushort4v o = { f2bf(y[0]), f2bf(y[1]), f2bf(y[2]), f2bf(y[3]) };
    *(ushort4v*)(hin + (size_t)g * K1 + lane * 4) = o;
    float s = x_skip[(size_t)g * CSK + lane];
    hin[(size_t)g * K1 + CIN + lane] = f2bf(s);
}

// ---- pre-swizzle W (f32 [K,N] row-major) into MFMA B-fragment order, bf16 ----
// layout: Wf[((kblk*16 + nfrag)*64 + lane)*8 + j]
//   k = kblk*32 + (lane>>4)*8 + j ; col = nfrag*16 + (lane&15)
__global__ __launch_bounds__(256) void wprep_kernel(
    const float* __restrict__ W, unsigned short* __restrict__ Wf, int K, int N)
{
    int id = blockIdx.x * 256 + threadIdx.x;
    if (id >= K * N) return;
    int j    = id & 7;
    int lane = (id >> 3) & 63;
    int n    = (id >> 9) & 15;
    int kblk = id >> 13;
    int k   = kblk * 32 + (lane >> 4) * 8 + j;
    int col = n * 16 + (lane & 15);
    Wf[id] = f2bf(W[(size_t)k * N + col]);
}

// ---------------- GEMM: out[M,256] = relu(A[M,K] @ W[K,256] + bias) ----------------
// block = 4 waves; block tile 64(M) x 256(N); wave tile 16 x 256 (16 C-frags)
template<int K, bool OUT_F32>
__global__ __launch_bounds__(256) void gemm_kernel(
    const unsigned short* __restrict__ A, const unsigned short* __restrict__ Wf,
    const float* __restrict__ bias, unsigned short* __restrict__ outb,
    float* __restrict__ outf)
{
    const int wave = threadIdx.x >> 6, lane = threadIdx.x & 63;
    const int m0 = blockIdx.x * 64 + wave * 16;
    const int l15 = lane & 15, lk = lane >> 4;

    f32x4 acc[16];
    #pragma unroll
    for (int n = 0; n < 16; ++n) acc[n] = f32x4{0.f, 0.f, 0.f, 0.f};

    const unsigned short* arow = A + (size_t)(m0 + l15) * K + lk * 8;
    for (int k0 = 0; k0 < K; k0 += 32) {
        bf16x8 a = *(const bf16x8*)(arow + k0);
        const unsigned short* wf = Wf + (size_t)(k0 >> 5) * (16 * 64 * 8) + lane * 8;
        #pragma unroll
        for (int n = 0; n < 16; ++n) {
            bf16x8 b = *(const bf16x8*)(wf + (size_t)n * 512);
            acc[n] = __builtin_amdgcn_mfma_f32_16x16x32_bf16(a, b, acc[n], 0, 0, 0);
        }
    }
    // C/D layout: col = lane&15, row = (lane>>4)*4 + r   [verified mapping]
    #pragma unroll
    for (int n = 0; n < 16; ++n) {
        int col = n * 16 + l15;
        float bv = bias[col];
        #pragma unroll
        for (int r = 0; r < 4; ++r) {
            float v = acc[n][r] + bv;
            v = fmaxf(v, 0.f);
            size_t o = (size_t)(m0 + lk * 4 + r) * HD + col;
            if (OUT_F32) outf[o] = v;
            else         outb[o] = f2bf(v);
        }
    }
}

// ---------------- tail: pos_skip passthrough + batch_skip ----------------
__global__ __launch_bounds__(256) void tail_kernel(
    const float* __restrict__ pos_skip, float* __restrict__ out)
{
    int i = blockIdx.x * 256 + threadIdx.x;
    const size_t o1 = (size_t)MTOT * HD;
    if (i < MTOT * 3) out[o1 + i] = pos_skip[i];
    if (i < MTOT)     out[o1 + (size_t)MTOT * 3 + i] = (float)(i >> 12); // i / 4096
}

extern "C" void kernel_launch(void* const* d_in, const int* in_sizes, int n_in,
                              void* d_out, int out_size, void* d_ws, size_t ws_size,
                              hipStream_t stream)
{
    const float* x        = (const float*)d_in[0];
    const float* pos      = (const float*)d_in[1];
    const float* x_skip   = (const float*)d_in[2];
    const float* pos_skip = (const float*)d_in[3];
    const float* W1       = (const float*)d_in[4];
    const float* b1       = (const float*)d_in[5];
    const float* W2       = (const float*)d_in[6];
    const float* b2       = (const float*)d_in[7];
    float* out = (float*)d_out;

    char* ws = (char*)d_ws;
    int*            idxb = (int*)(ws + IDX_OFF);
    float*          wgtb = (float*)(ws + WGT_OFF);
    unsigned short* W1f  = (unsigned short*)(ws + W1F_OFF);
    unsigned short* W2f  = (unsigned short*)(ws + W2F_OFF);
    unsigned short* hin  = (unsigned short*)(ws + HIN_OFF);
    unsigned short* h1   = (unsigned short*)(ws + H1_OFF);

    knn_kernel<<<BB * (NT / 256), 256, 0, stream>>>(pos, pos_skip, idxb, wgtb);
    wprep_kernel<<<(K1 * HD + 255) / 256, 256, 0, stream>>>(W1, W1f, K1, HD);
    wprep_kernel<<<(HD * HD + 255) / 256, 256, 0, stream>>>(W2, W2f, HD, HD);
    interp_kernel<<<MTOT / 4, 256, 0, stream>>>(x, x_skip, idxb, wgtb, hin);
    gemm_kernel<K1, false><<<MTOT / 64, 256, 0, stream>>>(hin, W1f, b1, h1, nullptr);
    gemm_kernel<HD, true ><<<MTOT / 64, 256, 0, stream>>>(h1, W2f, b2, nullptr, out);
    tail_kernel<<<(MTOT * 3 + 255) / 256, 256, 0, stream>>>(pos_skip, out);
}

// Round 3
// 226.700 us; speedup vs baseline: 1.3070x; 1.3070x over previous
//
#include <hip/hip_runtime.h>
#include <hip/hip_bf16.h>

// Problem constants (from reference)
#define BB   16
#define NS   1024
#define NT   4096
#define CIN  256
#define CSK  64
#define HD   256           // hidden dim / output cols
#define K1   (CIN + CSK)   // 320
#define MTOT (BB * NT)     // 65536

typedef __attribute__((ext_vector_type(4))) float f32x4;
typedef __attribute__((ext_vector_type(8))) __bf16 bf16x8;
typedef __attribute__((ext_vector_type(4))) unsigned short ushort4v;

// ws layout (bytes)
#define IDX_OFF 0u                    // int[MTOT*3]      = 786432
#define WGT_OFF 786432u               // float[MTOT*3]    = 786432
#define W1F_OFF 1572864u              // bf16[320*256]    = 163840
#define W2F_OFF 1736704u              // bf16[256*256]    = 131072
#define HIN_OFF 2097152u              // bf16[MTOT*320]   = 41943040
#define H1_OFF  44040192u             // bf16[MTOT*256]   = 33554432
// total ~77.6 MB

static __device__ __forceinline__ unsigned short f2bf(float f) {
    union { float f; unsigned int u; } v; v.f = f;
    unsigned int r = (v.u + 0x7FFFu + ((v.u >> 16) & 1u)) >> 16;
    return (unsigned short)r;
}

static __device__ __forceinline__ unsigned long long umin64(unsigned long long a, unsigned long long b) {
    return a < b ? a : b;
}
static __device__ __forceinline__ unsigned long long umax64(unsigned long long a, unsigned long long b) {
    return a > b ? a : b;
}

// ---------------- kNN (K=3) over per-cloud 1024 points ----------------
// 8 lanes per query (parts p = s mod 8); branchless top-3 via exact u64 keys
// key = (f32bits(d) << 32) | s  -- monotone in d (d >= 0), ties -> lowest s,
// matching jax.lax.top_k tie-breaking. Distance in the SAME difference form
// as the (passing) round-1 kernel: selection is exact.
#define KNN_P   8                 // parts per query
#define KNN_QPB (256 / KNN_P)     // 32 queries per block
__global__ __launch_bounds__(256) void knn_kernel(
    const float* __restrict__ pos, const float* __restrict__ pos_skip,
    int* __restrict__ idx_out, float* __restrict__ wgt_out)
{
    __shared__ float4 sp[NS];     // {x, y, z, pad}  16 KB
    const int blocks_per_cloud = NT / KNN_QPB;          // 128
    const int cloud = blockIdx.x / blocks_per_cloud;
    const int q = cloud * NT + (blockIdx.x % blocks_per_cloud) * KNN_QPB
                + (threadIdx.x >> 3);
    const int p = threadIdx.x & (KNN_P - 1);
    const float* pc = pos + (size_t)cloud * NS * 3;
    for (int i = threadIdx.x; i < NS; i += 256) {
        sp[i] = make_float4(pc[i * 3 + 0], pc[i * 3 + 1], pc[i * 3 + 2], 0.f);
    }
    __syncthreads();

    const float qx = pos_skip[q * 3 + 0];
    const float qy = pos_skip[q * 3 + 1];
    const float qz = pos_skip[q * 3 + 2];

    unsigned long long b0 = ~0ull, b1 = ~0ull, b2 = ~0ull;
    #pragma unroll 4
    for (int i = 0; i < NS / KNN_P; ++i) {
        const int s = i * KNN_P + p;
        float4 c = sp[s];
        float dx = qx - c.x, dy = qy - c.y, dz = qz - c.z;
        float d = dx * dx + dy * dy + dz * dz;
        unsigned long long key =
            ((unsigned long long)__float_as_uint(d) << 32) | (unsigned int)s;
        // branchless sorted-insert into (b0 <= b1 <= b2)
        unsigned long long t0 = umin64(b0, key), m0 = umax64(b0, key); b0 = t0;
        unsigned long long t1 = umin64(b1, m0),  m1 = umax64(b1, m0);  b1 = t1;
        b2 = umin64(b2, m1);
    }
    // merge partial top-3 across the 8 parts (lane bits 0..2)
    #pragma unroll
    for (int m = 1; m <= 4; m <<= 1) {
        unsigned long long o0 = __shfl_xor((long long)b0, m, 64);
        unsigned long long o1 = __shfl_xor((long long)b1, m, 64);
        unsigned long long o2 = __shfl_xor((long long)b2, m, 64);
        unsigned long long t0, m0, t1, m1;
        t0 = umin64(b0, o0); m0 = umax64(b0, o0); b0 = t0;
        t1 = umin64(b1, m0); m1 = umax64(b1, m0); b1 = t1;
        b2 = umin64(b2, m1);
        t0 = umin64(b0, o1); m0 = umax64(b0, o1); b0 = t0;
        t1 = umin64(b1, m0); m1 = umax64(b1, m0); b1 = t1;
        b2 = umin64(b2, m1);
        t0 = umin64(b0, o2); m0 = umax64(b0, o2); b0 = t0;
        t1 = umin64(b1, m0); m1 = umax64(b1, m0); b1 = t1;
        b2 = umin64(b2, m1);
    }
    if (p == 0) {
        const int s0 = (int)(b0 & 0xFFFFFFFFull);
        const int s1 = (int)(b1 & 0xFFFFFFFFull);
        const int s2 = (int)(b2 & 0xFFFFFFFFull);
        float d0 = __uint_as_float((unsigned int)(b0 >> 32));
        float d1 = __uint_as_float((unsigned int)(b1 >> 32));
        float d2 = __uint_as_float((unsigned int)(b2 >> 32));
        float w0 = 1.f / fmaxf(d0, 1e-16f);
        float w1 = 1.f / fmaxf(d1, 1e-16f);
        float w2 = 1.f / fmaxf(d2, 1e-16f);
        float inv = 1.f / (w0 + w1 + w2);
        idx_out[q * 3 + 0] = cloud * NS + s0;
        idx_out[q * 3 + 1] = cloud * NS + s1;
        idx_out[q * 3 + 2] = cloud * NS + s2;
        wgt_out[q * 3 + 0] = w0 * inv;
        wgt_out[q * 3 + 1] = w1 * inv;
        wgt_out[q * 3 + 2] = w2 * inv;
    }
}

// ------- interpolate + concat skip -> hin bf16 [MTOT, 320], row-major -------
__global__ __launch_bounds__(256) void interp_kernel(
    const float* __restrict__ x, const float* __restrict__ x_skip,
    const int* __restrict__ idx, const float* __restrict__ wgt,
    unsigned short* __restrict__ hin)
{
    const int g = blockIdx.x * 4 + (threadIdx.x >> 6);
    const int lane = threadIdx.x & 63;
    const int i0 = idx[g * 3 + 0], i1 = idx[g * 3 + 1], i2 = idx[g * 3 + 2];
    const float w0 = wgt[g * 3 + 0], w1 = wgt[g * 3 + 1], w2 = wgt[g * 3 + 2];
    const f32x4* r0 = (const f32x4*)(x + (size_t)i0 * CIN);
    const f32x4* r1 = (const f32x4*)(x + (size_t)i1 * CIN);
    const f32x4* r2 = (const f32x4*)(x + (size_t)i2 * CIN);
    f32x4 a = r0[lane], b = r1[lane], c = r2[lane];
    f32x4 y = a * w0 + b * w1 + c * w2;
    ushort4v o = { f2bf(y[0]), f2bf(y[1]), f2bf(y[2]), f2bf(y[3]) };
    *(ushort4v*)(hin + (size_t)g * K1 + lane * 4) = o;
    float s = x_skip[(size_t)g * CSK + lane];
    hin[(size_t)g * K1 + CIN + lane] = f2bf(s);
}

// ---- pre-swizzle W (f32 [K,N] row-major) into MFMA B-fragment order, bf16 ----
// layout: Wf[((kblk*16 + nfrag)*64 + lane)*8 + j]
//   k = kblk*32 + (lane>>4)*8 + j ; col = nfrag*16 + (lane&15)
__global__ __launch_bounds__(256) void wprep_kernel(
    const float* __restrict__ W, unsigned short* __restrict__ Wf, int K, int N)
{
    int id = blockIdx.x * 256 + threadIdx.x;
    if (id >= K * N) return;
    int j    = id & 7;
    int lane = (id >> 3) & 63;
    int n    = (id >> 9) & 15;
    int kblk = id >> 13;
    int k   = kblk * 32 + (lane >> 4) * 8 + j;
    int col = n * 16 + (lane & 15);
    Wf[id] = f2bf(W[(size_t)k * N + col]);
}

// ---------------- GEMM: out[M,256] = relu(A[M,K] @ W[K,256] + bias) ----------------
// block = 4 waves; block tile 64(M) x 256(N); wave tile 16 x 256 (16 C-frags)
template<int K, bool OUT_F32>
__global__ __launch_bounds__(256) void gemm_kernel(
    const unsigned short* __restrict__ A, const unsigned short* __restrict__ Wf,
    const float* __restrict__ bias, unsigned short* __restrict__ outb,
    float* __restrict__ outf)
{
    const int wave = threadIdx.x >> 6, lane = threadIdx.x & 63;
    const int m0 = blockIdx.x * 64 + wave * 16;
    const int l15 = lane & 15, lk = lane >> 4;

    f32x4 acc[16];
    #pragma unroll
    for (int n = 0; n < 16; ++n) acc[n] = f32x4{0.f, 0.f, 0.f, 0.f};

    const unsigned short* arow = A + (size_t)(m0 + l15) * K + lk * 8;
    for (int k0 = 0; k0 < K; k0 += 32) {
        bf16x8 a = *(const bf16x8*)(arow + k0);
        const unsigned short* wf = Wf + (size_t)(k0 >> 5) * (16 * 64 * 8) + lane * 8;
        #pragma unroll
        for (int n = 0; n < 16; ++n) {
            bf16x8 b = *(const bf16x8*)(wf + (size_t)n * 512);
            acc[n] = __builtin_amdgcn_mfma_f32_16x16x32_bf16(a, b, acc[n], 0, 0, 0);
        }
    }
    // C/D layout: col = lane&15, row = (lane>>4)*4 + r   [verified mapping]
    #pragma unroll
    for (int n = 0; n < 16; ++n) {
        int col = n * 16 + l15;
        float bv = bias[col];
        #pragma unroll
        for (int r = 0; r < 4; ++r) {
            float v = acc[n][r] + bv;
            v = fmaxf(v, 0.f);
            size_t o = (size_t)(m0 + lk * 4 + r) * HD + col;
            if (OUT_F32) outf[o] = v;
            else         outb[o] = f2bf(v);
        }
    }
}

// ---------------- tail: pos_skip passthrough + batch_skip ----------------
__global__ __launch_bounds__(256) void tail_kernel(
    const float* __restrict__ pos_skip, float* __restrict__ out)
{
    int i = blockIdx.x * 256 + threadIdx.x;
    const size_t o1 = (size_t)MTOT * HD;
    if (i < MTOT * 3) out[o1 + i] = pos_skip[i];
    if (i < MTOT)     out[o1 + (size_t)MTOT * 3 + i] = (float)(i >> 12); // i / 4096
}

extern "C" void kernel_launch(void* const* d_in, const int* in_sizes, int n_in,
                              void* d_out, int out_size, void* d_ws, size_t ws_size,
                              hipStream_t stream)
{
    const float* x        = (const float*)d_in[0];
    const float* pos      = (const float*)d_in[1];
    const float* x_skip   = (const float*)d_in[2];
    const float* pos_skip = (const float*)d_in[3];
    const float* W1       = (const float*)d_in[4];
    const float* b1       = (const float*)d_in[5];
    const float* W2       = (const float*)d_in[6];
    const float* b2       = (const float*)d_in[7];
    float* out = (float*)d_out;

    char* ws = (char*)d_ws;
    int*            idxb = (int*)(ws + IDX_OFF);
    float*          wgtb = (float*)(ws + WGT_OFF);
    unsigned short* W1f  = (unsigned short*)(ws + W1F_OFF);
    unsigned short* W2f  = (unsigned short*)(ws + W2F_OFF);
    unsigned short* hin  = (unsigned short*)(ws + HIN_OFF);
    unsigned short* h1   = (unsigned short*)(ws + H1_OFF);

    knn_kernel<<<BB * (NT / KNN_QPB), 256, 0, stream>>>(pos, pos_skip, idxb, wgtb);
    wprep_kernel<<<(K1 * HD + 255) / 256, 256, 0, stream>>>(W1, W1f, K1, HD);
    wprep_kernel<<<(HD * HD + 255) / 256, 256, 0, stream>>>(W2, W2f, HD, HD);
    interp_kernel<<<MTOT / 4, 256, 0, stream>>>(x, x_skip, idxb, wgtb, hin);
    gemm_kernel<K1, false><<<MTOT / 64, 256, 0, stream>>>(hin, W1f, b1, h1, nullptr);
    gemm_kernel<HD, true ><<<MTOT / 64, 256, 0, stream>>>(h1, W2f, b2, nullptr, out);
    tail_kernel<<<(MTOT * 3 + 255) / 256, 256, 0, stream>>>(pos_skip, out);
}

// Round 4
// 141.052 us; speedup vs baseline: 2.1006x; 1.6072x over previous
//
#include <hip/hip_runtime.h>
#include <hip/hip_bf16.h>

// Problem constants (from reference)
#define BB   16
#define NS   1024
#define NT   4096
#define CIN  256
#define CSK  64
#define HD   256           // hidden dim / output cols
#define K1   (CIN + CSK)   // 320
#define MTOT (BB * NT)     // 65536

typedef __attribute__((ext_vector_type(4))) float f32x4;
typedef __attribute__((ext_vector_type(8))) __bf16 bf16x8;
typedef __attribute__((ext_vector_type(4))) unsigned short ushort4v;

// ws layout (bytes)
#define IDX_OFF 0u                    // int[MTOT*3]      = 786432
#define WGT_OFF 786432u               // float[MTOT*3]    = 786432
#define W1F_OFF 1572864u              // bf16[320*256]    = 163840
#define W2F_OFF 1736704u              // bf16[256*256]    = 131072
#define HIN_OFF 2097152u              // bf16[MTOT*320]   = 41943040
#define H1_OFF  44040192u             // bf16[MTOT*256]   = 33554432
// total ~77.6 MB

static __device__ __forceinline__ unsigned short f2bf(float f) {
    union { float f; unsigned int u; } v; v.f = f;
    unsigned int r = (v.u + 0x7FFFu + ((v.u >> 16) & 1u)) >> 16;
    return (unsigned short)r;
}

static __device__ __forceinline__ unsigned long long umin64(unsigned long long a, unsigned long long b) {
    return a < b ? a : b;
}
static __device__ __forceinline__ unsigned long long umax64(unsigned long long a, unsigned long long b) {
    return a > b ? a : b;
}

// async global->LDS, 16 B per lane; dest = wave-uniform base + lane*16
static __device__ __forceinline__ void gll16(const unsigned short* g, unsigned short* l) {
    __builtin_amdgcn_global_load_lds(
        (const __attribute__((address_space(1))) unsigned int*)g,
        (__attribute__((address_space(3))) unsigned int*)l,
        16, 0, 0);
}

// ---------------- kNN (K=3) over per-cloud 1024 points ----------------
// 8 lanes per query; branchless top-3 via exact u64 keys (d-bits<<32 | idx).
#define KNN_P   8
#define KNN_QPB (256 / KNN_P)     // 32 queries per block
__global__ __launch_bounds__(256) void knn_kernel(
    const float* __restrict__ pos, const float* __restrict__ pos_skip,
    int* __restrict__ idx_out, float* __restrict__ wgt_out)
{
    __shared__ float4 sp[NS];
    const int blocks_per_cloud = NT / KNN_QPB;          // 128
    const int cloud = blockIdx.x / blocks_per_cloud;
    const int q = cloud * NT + (blockIdx.x % blocks_per_cloud) * KNN_QPB
                + (threadIdx.x >> 3);
    const int p = threadIdx.x & (KNN_P - 1);
    const float* pc = pos + (size_t)cloud * NS * 3;
    for (int i = threadIdx.x; i < NS; i += 256) {
        sp[i] = make_float4(pc[i * 3 + 0], pc[i * 3 + 1], pc[i * 3 + 2], 0.f);
    }
    __syncthreads();

    const float qx = pos_skip[q * 3 + 0];
    const float qy = pos_skip[q * 3 + 1];
    const float qz = pos_skip[q * 3 + 2];

    unsigned long long b0 = ~0ull, b1 = ~0ull, b2 = ~0ull;
    #pragma unroll 4
    for (int i = 0; i < NS / KNN_P; ++i) {
        const int s = i * KNN_P + p;
        float4 c = sp[s];
        float dx = qx - c.x, dy = qy - c.y, dz = qz - c.z;
        float d = dx * dx + dy * dy + dz * dz;
        unsigned long long key =
            ((unsigned long long)__float_as_uint(d) << 32) | (unsigned int)s;
        unsigned long long t0 = umin64(b0, key), m0 = umax64(b0, key); b0 = t0;
        unsigned long long t1 = umin64(b1, m0),  m1 = umax64(b1, m0);  b1 = t1;
        b2 = umin64(b2, m1);
    }
    #pragma unroll
    for (int m = 1; m <= 4; m <<= 1) {
        unsigned long long o0 = __shfl_xor((long long)b0, m, 64);
        unsigned long long o1 = __shfl_xor((long long)b1, m, 64);
        unsigned long long o2 = __shfl_xor((long long)b2, m, 64);
        unsigned long long t0, m0, t1, m1;
        t0 = umin64(b0, o0); m0 = umax64(b0, o0); b0 = t0;
        t1 = umin64(b1, m0); m1 = umax64(b1, m0); b1 = t1;
        b2 = umin64(b2, m1);
        t0 = umin64(b0, o1); m0 = umax64(b0, o1); b0 = t0;
        t1 = umin64(b1, m0); m1 = umax64(b1, m0); b1 = t1;
        b2 = umin64(b2, m1);
        t0 = umin64(b0, o2); m0 = umax64(b0, o2); b0 = t0;
        t1 = umin64(b1, m0); m1 = umax64(b1, m0); b1 = t1;
        b2 = umin64(b2, m1);
    }
    if (p == 0) {
        const int s0 = (int)(b0 & 0xFFFFFFFFull);
        const int s1 = (int)(b1 & 0xFFFFFFFFull);
        const int s2 = (int)(b2 & 0xFFFFFFFFull);
        float d0 = __uint_as_float((unsigned int)(b0 >> 32));
        float d1 = __uint_as_float((unsigned int)(b1 >> 32));
        float d2 = __uint_as_float((unsigned int)(b2 >> 32));
        float w0 = 1.f / fmaxf(d0, 1e-16f);
        float w1 = 1.f / fmaxf(d1, 1e-16f);
        float w2 = 1.f / fmaxf(d2, 1e-16f);
        float inv = 1.f / (w0 + w1 + w2);
        idx_out[q * 3 + 0] = cloud * NS + s0;
        idx_out[q * 3 + 1] = cloud * NS + s1;
        idx_out[q * 3 + 2] = cloud * NS + s2;
        wgt_out[q * 3 + 0] = w0 * inv;
        wgt_out[q * 3 + 1] = w1 * inv;
        wgt_out[q * 3 + 2] = w2 * inv;
    }
}

// ------- interpolate + concat skip -> hin bf16 [MTOT, 320], row-major -------
__global__ __launch_bounds__(256) void interp_kernel(
    const float* __restrict__ x, const float* __restrict__ x_skip,
    const int* __restrict__ idx, const float* __restrict__ wgt,
    unsigned short* __restrict__ hin)
{
    const int g = blockIdx.x * 4 + (threadIdx.x >> 6);
    const int lane = threadIdx.x & 63;
    const int i0 = idx[g * 3 + 0], i1 = idx[g * 3 + 1], i2 = idx[g * 3 + 2];
    const float w0 = wgt[g * 3 + 0], w1 = wgt[g * 3 + 1], w2 = wgt[g * 3 + 2];
    const f32x4* r0 = (const f32x4*)(x + (size_t)i0 * CIN);
    const f32x4* r1 = (const f32x4*)(x + (size_t)i1 * CIN);
    const f32x4* r2 = (const f32x4*)(x + (size_t)i2 * CIN);
    f32x4 a = r0[lane], b = r1[lane], c = r2[lane];
    f32x4 y = a * w0 + b * w1 + c * w2;
    ushort4v o = { f2bf(y[0]), f2bf(y[1]), f2bf(y[2]), f2bf(y[3]) };
    *(ushort4v*)(hin + (size_t)g * K1 + lane * 4) = o;
    float s = x_skip[(size_t)g * CSK + lane];
    hin[(size_t)g * K1 + CIN + lane] = f2bf(s);
}

// ---- pre-swizzle W (f32 [K,N] row-major) into MFMA B-fragment order, bf16 ----
// layout: Wf[kblk][n(16)][lane(64)][8]
//   k = kblk*32 + (lane>>4)*8 + j ; col = n*16 + (lane&15)
__global__ __launch_bounds__(256) void wprep_kernel(
    const float* __restrict__ W, unsigned short* __restrict__ Wf, int K, int N)
{
    int id = blockIdx.x * 256 + threadIdx.x;
    if (id >= K * N) return;
    int j    = id & 7;
    int lane = (id >> 3) & 63;
    int n    = (id >> 9) & 15;
    int kblk = id >> 13;
    int k   = kblk * 32 + (lane >> 4) * 8 + j;
    int col = n * 16 + (lane & 15);
    Wf[id] = f2bf(W[(size_t)k * N + col]);
}

// ---------------- GEMM: out[M,256] = relu(A[M,K] @ W[K,256] + bias) ----------------
// Block tile 128M x 128N, 4 waves at 64x64 each. B staged in LDS (dbuf) via
// global_load_lds from fragment-linear Wf; A direct per-lane global frags.
template<int K, bool OUT_F32>
__global__ __launch_bounds__(256, 3) void gemm_kernel(
    const unsigned short* __restrict__ A, const unsigned short* __restrict__ Wf,
    const float* __restrict__ bias, unsigned short* __restrict__ outb,
    float* __restrict__ outf)
{
    constexpr int NKB = K / 32;
    __shared__ __align__(16) unsigned short ldsB[2][8 * 512]; // [buf][frag*512+lane*8]

    const int tid = threadIdx.x;
    const int w = tid >> 6, lane = tid & 63;
    const int wm = w >> 1, wn = w & 1;
    const int l15 = lane & 15, lk = lane >> 4;
    const int bm = blockIdx.x >> 1, bn = blockIdx.x & 1;

    // staging: wave w copies fragment pieces {2w, 2w+1} of the 8-frag chunk
    const unsigned short* wsrc = Wf + bn * 4096 + w * 1024 + lane * 8;
    unsigned short* ld0 = &ldsB[0][w * 1024];
    unsigned short* ld1 = &ldsB[1][w * 1024];

    gll16(wsrc,       ld0);
    gll16(wsrc + 512, ld0 + 512);

    const unsigned short* arow = A + (size_t)(bm * 128 + wm * 64 + l15) * K + lk * 8;

    f32x4 acc[4][4];
    #pragma unroll
    for (int mf = 0; mf < 4; ++mf)
        #pragma unroll
        for (int nf = 0; nf < 4; ++nf)
            acc[mf][nf] = f32x4{0.f, 0.f, 0.f, 0.f};

    for (int kb = 0; kb < NKB; ++kb) {
        __syncthreads();   // staged buf[kb&1] ready; prior reads of buf[(kb+1)&1] done
        if (kb + 1 < NKB) {
            const unsigned short* s = wsrc + (size_t)(kb + 1) * 8192;
            unsigned short* d = (kb & 1) ? ld0 : ld1;      // next buf = (kb+1)&1
            gll16(s,       d);
            gll16(s + 512, d + 512);
        }
        bf16x8 a[4], b[4];
        #pragma unroll
        for (int mf = 0; mf < 4; ++mf)
            a[mf] = *(const bf16x8*)(arow + (size_t)mf * 16 * K + kb * 32);
        #pragma unroll
        for (int nf = 0; nf < 4; ++nf)
            b[nf] = *(const bf16x8*)(&ldsB[kb & 1][(wn * 4 + nf) * 512 + lane * 8]);
        #pragma unroll
        for (int mf = 0; mf < 4; ++mf)
            #pragma unroll
            for (int nf = 0; nf < 4; ++nf)
                acc[mf][nf] = __builtin_amdgcn_mfma_f32_16x16x32_bf16(
                    a[mf], b[nf], acc[mf][nf], 0, 0, 0);
    }

    // epilogue: col = ...+l15, row = ...+lk*4+r  [verified mapping]
    const int rbase = bm * 128 + wm * 64 + lk * 4;
    const int cbase = bn * 128 + wn * 64 + l15;
    #pragma unroll
    for (int nf = 0; nf < 4; ++nf) {
        const int col = cbase + nf * 16;
        const float bv = bias[col];
        #pragma unroll
        for (int mf = 0; mf < 4; ++mf) {
            #pragma unroll
            for (int r = 0; r < 4; ++r) {
                float v = fmaxf(acc[mf][nf][r] + bv, 0.f);
                size_t o = (size_t)(rbase + mf * 16 + r) * HD + col;
                if (OUT_F32) outf[o] = v;
                else         outb[o] = f2bf(v);
            }
        }
    }
}

// ---------------- tail: pos_skip passthrough + batch_skip ----------------
__global__ __launch_bounds__(256) void tail_kernel(
    const float* __restrict__ pos_skip, float* __restrict__ out)
{
    int i = blockIdx.x * 256 + threadIdx.x;
    const size_t o1 = (size_t)MTOT * HD;
    if (i < MTOT * 3) out[o1 + i] = pos_skip[i];
    if (i < MTOT)     out[o1 + (size_t)MTOT * 3 + i] = (float)(i >> 12); // i / 4096
}

extern "C" void kernel_launch(void* const* d_in, const int* in_sizes, int n_in,
                              void* d_out, int out_size, void* d_ws, size_t ws_size,
                              hipStream_t stream)
{
    const float* x        = (const float*)d_in[0];
    const float* pos      = (const float*)d_in[1];
    const float* x_skip   = (const float*)d_in[2];
    const float* pos_skip = (const float*)d_in[3];
    const float* W1       = (const float*)d_in[4];
    const float* b1       = (const float*)d_in[5];
    const float* W2       = (const float*)d_in[6];
    const float* b2       = (const float*)d_in[7];
    float* out = (float*)d_out;

    char* ws = (char*)d_ws;
    int*            idxb = (int*)(ws + IDX_OFF);
    float*          wgtb = (float*)(ws + WGT_OFF);
    unsigned short* W1f  = (unsigned short*)(ws + W1F_OFF);
    unsigned short* W2f  = (unsigned short*)(ws + W2F_OFF);
    unsigned short* hin  = (unsigned short*)(ws + HIN_OFF);
    unsigned short* h1   = (unsigned short*)(ws + H1_OFF);

    knn_kernel<<<BB * (NT / KNN_QPB), 256, 0, stream>>>(pos, pos_skip, idxb, wgtb);
    wprep_kernel<<<(K1 * HD + 255) / 256, 256, 0, stream>>>(W1, W1f, K1, HD);
    wprep_kernel<<<(HD * HD + 255) / 256, 256, 0, stream>>>(W2, W2f, HD, HD);
    interp_kernel<<<MTOT / 4, 256, 0, stream>>>(x, x_skip, idxb, wgtb, hin);
    gemm_kernel<K1, false><<<(MTOT / 128) * 2, 256, 0, stream>>>(hin, W1f, b1, h1, nullptr);
    gemm_kernel<HD, true ><<<(MTOT / 128) * 2, 256, 0, stream>>>(h1, W2f, b2, nullptr, out);
    tail_kernel<<<(MTOT * 3 + 255) / 256, 256, 0, stream>>>(pos_skip, out);
}

// Round 5
// 123.901 us; speedup vs baseline: 2.3914x; 1.1384x over previous
//
#include <hip/hip_runtime.h>
#include <hip/hip_bf16.h>

// Problem constants (from reference)
#define BB   16
#define NS   1024
#define NT   4096
#define CIN  256
#define CSK  64
#define HD   256           // hidden dim / output cols
#define K1   (CIN + CSK)   // 320
#define MTOT (BB * NT)     // 65536

typedef __attribute__((ext_vector_type(4))) float f32x4;
typedef __attribute__((ext_vector_type(8))) __bf16 bf16x8;
typedef __attribute__((ext_vector_type(4))) unsigned short ushort4v;

// ws layout (bytes)
#define IDX_OFF 0u                    // int[MTOT*3]      = 786432
#define WGT_OFF 786432u               // float[MTOT*3]    = 786432
#define W1F_OFF 1572864u              // bf16[320*256]    = 163840
#define W2F_OFF 1736704u              // bf16[256*256]    = 131072
#define HIN_OFF 2097152u              // bf16[MTOT*320]   = 41943040
#define H1_OFF  44040192u             // bf16[MTOT*256]   = 33554432
// total ~77.6 MB

static __device__ __forceinline__ unsigned short f2bf(float f) {
    union { float f; unsigned int u; } v; v.f = f;
    unsigned int r = (v.u + 0x7FFFu + ((v.u >> 16) & 1u)) >> 16;
    return (unsigned short)r;
}

// async global->LDS, 16 B per lane; dest = wave-uniform base + lane*16
static __device__ __forceinline__ void gll16(const unsigned short* g, unsigned short* l) {
    __builtin_amdgcn_global_load_lds(
        (const __attribute__((address_space(1))) unsigned int*)g,
        (__attribute__((address_space(3))) unsigned int*)l,
        16, 0, 0);
}

// ---------------- kNN (K=3) over per-cloud 1024 points ----------------
// 8 lanes per query. Exact lex key packed in an integer-valued DOUBLE:
//   key = (double)f32bits(d) * 1024 + s    (< 2^41, exact in f64)
// monotone in d (d >= 0), ties -> lowest s (matches lax.top_k). Top-3
// maintained branchlessly with single-instr v_min_f64/v_max_f64 (5/insert
// vs 15 for the u64 cmp+cndmask network).
#define KNN_P   8
#define KNN_QPB (256 / KNN_P)     // 32 queries per block
__global__ __launch_bounds__(256) void knn_kernel(
    const float* __restrict__ pos, const float* __restrict__ pos_skip,
    int* __restrict__ idx_out, float* __restrict__ wgt_out)
{
    __shared__ float4 sp[NS];
    const int blocks_per_cloud = NT / KNN_QPB;          // 128
    const int cloud = blockIdx.x / blocks_per_cloud;
    const int q = cloud * NT + (blockIdx.x % blocks_per_cloud) * KNN_QPB
                + (threadIdx.x >> 3);
    const int p = threadIdx.x & (KNN_P - 1);
    const float* pc = pos + (size_t)cloud * NS * 3;
    for (int i = threadIdx.x; i < NS; i += 256) {
        sp[i] = make_float4(pc[i * 3 + 0], pc[i * 3 + 1], pc[i * 3 + 2], 0.f);
    }
    __syncthreads();

    const float qx = pos_skip[q * 3 + 0];
    const float qy = pos_skip[q * 3 + 1];
    const float qz = pos_skip[q * 3 + 2];

    double b0 = 1e300, b1 = 1e300, b2 = 1e300;
    double si = (double)p;                       // s as f64 induction var
    #pragma unroll 4
    for (int i = 0; i < NS / KNN_P; ++i) {
        const int s = i * KNN_P + p;
        float4 c = sp[s];
        float dx = qx - c.x, dy = qy - c.y, dz = qz - c.z;
        float d = dx * dx + dy * dy + dz * dz;   // same expr as passing rounds
        double key = fma((double)__float_as_uint(d), 1024.0, si);
        si += (double)KNN_P;
        double t0 = fmin(b0, key), m0 = fmax(b0, key); b0 = t0;
        double t1 = fmin(b1, m0),  m1 = fmax(b1, m0);  b1 = t1;
        b2 = fmin(b2, m1);
    }
    // merge partial top-3 across the 8 parts (lane bits 0..2)
    #pragma unroll
    for (int m = 1; m <= 4; m <<= 1) {
        double o0 = __shfl_xor(b0, m, 64);
        double o1 = __shfl_xor(b1, m, 64);
        double o2 = __shfl_xor(b2, m, 64);
        double t0, m0, t1, m1;
        t0 = fmin(b0, o0); m0 = fmax(b0, o0); b0 = t0;
        t1 = fmin(b1, m0); m1 = fmax(b1, m0); b1 = t1;
        b2 = fmin(b2, m1);
        t0 = fmin(b0, o1); m0 = fmax(b0, o1); b0 = t0;
        t1 = fmin(b1, m0); m1 = fmax(b1, m0); b1 = t1;
        b2 = fmin(b2, m1);
        t0 = fmin(b0, o2); m0 = fmax(b0, o2); b0 = t0;
        t1 = fmin(b1, m0); m1 = fmax(b1, m0); b1 = t1;
        b2 = fmin(b2, m1);
    }
    if (p == 0) {
        unsigned long long k0 = (unsigned long long)b0;
        unsigned long long k1 = (unsigned long long)b1;
        unsigned long long k2 = (unsigned long long)b2;
        const int s0 = (int)(k0 & 1023ull);
        const int s1 = (int)(k1 & 1023ull);
        const int s2 = (int)(k2 & 1023ull);
        float d0 = __uint_as_float((unsigned int)(k0 >> 10));
        float d1 = __uint_as_float((unsigned int)(k1 >> 10));
        float d2 = __uint_as_float((unsigned int)(k2 >> 10));
        float w0 = 1.f / fmaxf(d0, 1e-16f);
        float w1 = 1.f / fmaxf(d1, 1e-16f);
        float w2 = 1.f / fmaxf(d2, 1e-16f);
        float inv = 1.f / (w0 + w1 + w2);
        idx_out[q * 3 + 0] = cloud * NS + s0;
        idx_out[q * 3 + 1] = cloud * NS + s1;
        idx_out[q * 3 + 2] = cloud * NS + s2;
        wgt_out[q * 3 + 0] = w0 * inv;
        wgt_out[q * 3 + 1] = w1 * inv;
        wgt_out[q * 3 + 2] = w2 * inv;
    }
}

// ------- interpolate + concat skip -> hin bf16 [MTOT, 320], row-major -------
__global__ __launch_bounds__(256) void interp_kernel(
    const float* __restrict__ x, const float* __restrict__ x_skip,
    const int* __restrict__ idx, const float* __restrict__ wgt,
    unsigned short* __restrict__ hin)
{
    const int g = blockIdx.x * 4 + (threadIdx.x >> 6);
    const int lane = threadIdx.x & 63;
    const int i0 = idx[g * 3 + 0], i1 = idx[g * 3 + 1], i2 = idx[g * 3 + 2];
    const float w0 = wgt[g * 3 + 0], w1 = wgt[g * 3 + 1], w2 = wgt[g * 3 + 2];
    const f32x4* r0 = (const f32x4*)(x + (size_t)i0 * CIN);
    const f32x4* r1 = (const f32x4*)(x + (size_t)i1 * CIN);
    const f32x4* r2 = (const f32x4*)(x + (size_t)i2 * CIN);
    f32x4 a = r0[lane], b = r1[lane], c = r2[lane];
    f32x4 y = a * w0 + b * w1 + c * w2;
    ushort4v o = { f2bf(y[0]), f2bf(y[1]), f2bf(y[2]), f2bf(y[3]) };
    *(ushort4v*)(hin + (size_t)g * K1 + lane * 4) = o;
    float s = x_skip[(size_t)g * CSK + lane];
    hin[(size_t)g * K1 + CIN + lane] = f2bf(s);
}

// ---- prep: W1/W2 swizzle into MFMA B-fragment order + out tail section ----
// Wf layout: Wf[kblk][n(16)][lane(64)][8]
//   k = kblk*32 + (lane>>4)*8 + j ; col = n*16 + (lane&15)
#define PREP_B1 (K1 * HD / 256)         // 320 blocks for W1f
#define PREP_B2 (HD * HD / 256)         // 256 blocks for W2f
#define PREP_B3 ((MTOT * 3) / 256)      // 768 blocks for tail
__global__ __launch_bounds__(256) void prep_kernel(
    const float* __restrict__ W1, const float* __restrict__ W2,
    const float* __restrict__ pos_skip,
    unsigned short* __restrict__ W1f, unsigned short* __restrict__ W2f,
    float* __restrict__ out)
{
    const int b = blockIdx.x;
    if (b < PREP_B1 + PREP_B2) {
        const bool is1 = b < PREP_B1;
        const int id = (is1 ? b : b - PREP_B1) * 256 + threadIdx.x;
        const int j    = id & 7;
        const int lane = (id >> 3) & 63;
        const int n    = (id >> 9) & 15;
        const int kblk = id >> 13;
        const int k   = kblk * 32 + (lane >> 4) * 8 + j;
        const int col = n * 16 + (lane & 15);
        if (is1) W1f[id] = f2bf(W1[(size_t)k * HD + col]);
        else     W2f[id] = f2bf(W2[(size_t)k * HD + col]);
    } else {
        const int i = (b - PREP_B1 - PREP_B2) * 256 + threadIdx.x;
        const size_t o1 = (size_t)MTOT * HD;
        out[o1 + i] = pos_skip[i];                                  // i < MTOT*3
        if (i < MTOT) out[o1 + (size_t)MTOT * 3 + i] = (float)(i >> 12);
    }
}

// ---------------- GEMM: out[M,256] = relu(A[M,K] @ W[K,256] + bias) ----------------
// Block tile 128M x 128N, 4 waves at 64x64 each. B staged in LDS (dbuf) via
// global_load_lds from fragment-linear Wf; A direct per-lane global frags.
template<int K, bool OUT_F32>
__global__ __launch_bounds__(256, 3) void gemm_kernel(
    const unsigned short* __restrict__ A, const unsigned short* __restrict__ Wf,
    const float* __restrict__ bias, unsigned short* __restrict__ outb,
    float* __restrict__ outf)
{
    constexpr int NKB = K / 32;
    __shared__ __align__(16) unsigned short ldsB[2][8 * 512]; // [buf][frag*512+lane*8]

    const int tid = threadIdx.x;
    const int w = tid >> 6, lane = tid & 63;
    const int wm = w >> 1, wn = w & 1;
    const int l15 = lane & 15, lk = lane >> 4;
    const int bm = blockIdx.x >> 1, bn = blockIdx.x & 1;

    // staging: wave w copies fragment pieces {2w, 2w+1} of the 8-frag chunk
    const unsigned short* wsrc = Wf + bn * 4096 + w * 1024 + lane * 8;
    unsigned short* ld0 = &ldsB[0][w * 1024];
    unsigned short* ld1 = &ldsB[1][w * 1024];

    gll16(wsrc,       ld0);
    gll16(wsrc + 512, ld0 + 512);

    const unsigned short* arow = A + (size_t)(bm * 128 + wm * 64 + l15) * K + lk * 8;

    f32x4 acc[4][4];
    #pragma unroll
    for (int mf = 0; mf < 4; ++mf)
        #pragma unroll
        for (int nf = 0; nf < 4; ++nf)
            acc[mf][nf] = f32x4{0.f, 0.f, 0.f, 0.f};

    for (int kb = 0; kb < NKB; ++kb) {
        __syncthreads();   // staged buf[kb&1] ready; prior reads of buf[(kb+1)&1] done
        if (kb + 1 < NKB) {
            const unsigned short* s = wsrc + (size_t)(kb + 1) * 8192;
            unsigned short* d = (kb & 1) ? ld0 : ld1;      // next buf = (kb+1)&1
            gll16(s,       d);
            gll16(s + 512, d + 512);
        }
        bf16x8 a[4], b[4];
        #pragma unroll
        for (int mf = 0; mf < 4; ++mf)
            a[mf] = *(const bf16x8*)(arow + (size_t)mf * 16 * K + kb * 32);
        #pragma unroll
        for (int nf = 0; nf < 4; ++nf)
            b[nf] = *(const bf16x8*)(&ldsB[kb & 1][(wn * 4 + nf) * 512 + lane * 8]);
        #pragma unroll
        for (int mf = 0; mf < 4; ++mf)
            #pragma unroll
            for (int nf = 0; nf < 4; ++nf)
                acc[mf][nf] = __builtin_amdgcn_mfma_f32_16x16x32_bf16(
                    a[mf], b[nf], acc[mf][nf], 0, 0, 0);
    }

    // epilogue: col = ...+l15, row = ...+lk*4+r  [verified mapping]
    const int rbase = bm * 128 + wm * 64 + lk * 4;
    const int cbase = bn * 128 + wn * 64 + l15;
    #pragma unroll
    for (int nf = 0; nf < 4; ++nf) {
        const int col = cbase + nf * 16;
        const float bv = bias[col];
        #pragma unroll
        for (int mf = 0; mf < 4; ++mf) {
            #pragma unroll
            for (int r = 0; r < 4; ++r) {
                float v = fmaxf(acc[mf][nf][r] + bv, 0.f);
                size_t o = (size_t)(rbase + mf * 16 + r) * HD + col;
                if (OUT_F32) outf[o] = v;
                else         outb[o] = f2bf(v);
            }
        }
    }
}

extern "C" void kernel_launch(void* const* d_in, const int* in_sizes, int n_in,
                              void* d_out, int out_size, void* d_ws, size_t ws_size,
                              hipStream_t stream)
{
    const float* x        = (const float*)d_in[0];
    const float* pos      = (const float*)d_in[1];
    const float* x_skip   = (const float*)d_in[2];
    const float* pos_skip = (const float*)d_in[3];
    const float* W1       = (const float*)d_in[4];
    const float* b1       = (const float*)d_in[5];
    const float* W2       = (const float*)d_in[6];
    const float* b2       = (const float*)d_in[7];
    float* out = (float*)d_out;

    char* ws = (char*)d_ws;
    int*            idxb = (int*)(ws + IDX_OFF);
    float*          wgtb = (float*)(ws + WGT_OFF);
    unsigned short* W1f  = (unsigned short*)(ws + W1F_OFF);
    unsigned short* W2f  = (unsigned short*)(ws + W2F_OFF);
    unsigned short* hin  = (unsigned short*)(ws + HIN_OFF);
    unsigned short* h1   = (unsigned short*)(ws + H1_OFF);

    knn_kernel<<<BB * (NT / KNN_QPB), 256, 0, stream>>>(pos, pos_skip, idxb, wgtb);
    prep_kernel<<<PREP_B1 + PREP_B2 + PREP_B3, 256, 0, stream>>>(
        W1, W2, pos_skip, W1f, W2f, out);
    interp_kernel<<<MTOT / 4, 256, 0, stream>>>(x, x_skip, idxb, wgtb, hin);
    gemm_kernel<K1, false><<<(MTOT / 128) * 2, 256, 0, stream>>>(hin, W1f, b1, h1, nullptr);
    gemm_kernel<HD, true ><<<(MTOT / 128) * 2, 256, 0, stream>>>(h1, W2f, b2, nullptr, out);
}

// Round 6
// 103.302 us; speedup vs baseline: 2.8683x; 1.1994x over previous
//
#include <hip/hip_runtime.h>
#include <hip/hip_bf16.h>

// Problem constants (from reference)
#define BB   16
#define NS   1024
#define NT   4096
#define CIN  256
#define CSK  64
#define HD   256           // hidden dim / output cols
#define K1   (CIN + CSK)   // 320
#define MTOT (BB * NT)     // 65536

typedef __attribute__((ext_vector_type(4))) float f32x4;
typedef __attribute__((ext_vector_type(8))) __bf16 bf16x8;
typedef __attribute__((ext_vector_type(4))) unsigned short ushort4v;

// ws layout (bytes)
#define IDX_OFF 0u                    // int[MTOT*3]      = 786432
#define WGT_OFF 786432u               // float[MTOT*3]    = 786432
#define W1F_OFF 1572864u              // bf16[320*256]    = 163840
#define W2F_OFF 1736704u              // bf16[256*256]    = 131072
#define H1_OFF  2097152u              // bf16[MTOT*256]   = 33554432
// total ~35.7 MB (hin eliminated)

static __device__ __forceinline__ unsigned short f2bf(float f) {
    union { float f; unsigned int u; } v; v.f = f;
    unsigned int r = (v.u + 0x7FFFu + ((v.u >> 16) & 1u)) >> 16;
    return (unsigned short)r;
}

// async global->LDS, 16 B per lane; dest = wave-uniform base (+ lane*16 by HW)
static __device__ __forceinline__ void gll16(const unsigned short* g, unsigned short* l) {
    __builtin_amdgcn_global_load_lds(
        (const __attribute__((address_space(1))) unsigned int*)g,
        (__attribute__((address_space(3))) unsigned int*)l,
        16, 0, 0);
}

// ---------------- kNN (K=3) over per-cloud 1024 points ----------------
// 8 lanes per query. Exact lex key packed in an integer-valued DOUBLE:
//   key = (double)f32bits(d) * 1024 + s    (< 2^41, exact in f64)
// monotone in d (d >= 0), ties -> lowest s (matches lax.top_k).
#define KNN_P   8
#define KNN_QPB (256 / KNN_P)     // 32 queries per block
__global__ __launch_bounds__(256) void knn_kernel(
    const float* __restrict__ pos, const float* __restrict__ pos_skip,
    int* __restrict__ idx_out, float* __restrict__ wgt_out)
{
    __shared__ float4 sp[NS];
    const int blocks_per_cloud = NT / KNN_QPB;          // 128
    const int cloud = blockIdx.x / blocks_per_cloud;
    const int q = cloud * NT + (blockIdx.x % blocks_per_cloud) * KNN_QPB
                + (threadIdx.x >> 3);
    const int p = threadIdx.x & (KNN_P - 1);
    const float* pc = pos + (size_t)cloud * NS * 3;
    for (int i = threadIdx.x; i < NS; i += 256) {
        sp[i] = make_float4(pc[i * 3 + 0], pc[i * 3 + 1], pc[i * 3 + 2], 0.f);
    }
    __syncthreads();

    const float qx = pos_skip[q * 3 + 0];
    const float qy = pos_skip[q * 3 + 1];
    const float qz = pos_skip[q * 3 + 2];

    double b0 = 1e300, b1 = 1e300, b2 = 1e300;
    double si = (double)p;
    #pragma unroll 4
    for (int i = 0; i < NS / KNN_P; ++i) {
        const int s = i * KNN_P + p;
        float4 c = sp[s];
        float dx = qx - c.x, dy = qy - c.y, dz = qz - c.z;
        float d = dx * dx + dy * dy + dz * dz;
        double key = fma((double)__float_as_uint(d), 1024.0, si);
        si += (double)KNN_P;
        double t0 = fmin(b0, key), m0 = fmax(b0, key); b0 = t0;
        double t1 = fmin(b1, m0),  m1 = fmax(b1, m0);  b1 = t1;
        b2 = fmin(b2, m1);
    }
    #pragma unroll
    for (int m = 1; m <= 4; m <<= 1) {
        double o0 = __shfl_xor(b0, m, 64);
        double o1 = __shfl_xor(b1, m, 64);
        double o2 = __shfl_xor(b2, m, 64);
        double t0, m0, t1, m1;
        t0 = fmin(b0, o0); m0 = fmax(b0, o0); b0 = t0;
        t1 = fmin(b1, m0); m1 = fmax(b1, m0); b1 = t1;
        b2 = fmin(b2, m1);
        t0 = fmin(b0, o1); m0 = fmax(b0, o1); b0 = t0;
        t1 = fmin(b1, m0); m1 = fmax(b1, m0); b1 = t1;
        b2 = fmin(b2, m1);
        t0 = fmin(b0, o2); m0 = fmax(b0, o2); b0 = t0;
        t1 = fmin(b1, m0); m1 = fmax(b1, m0); b1 = t1;
        b2 = fmin(b2, m1);
    }
    if (p == 0) {
        unsigned long long k0 = (unsigned long long)b0;
        unsigned long long k1 = (unsigned long long)b1;
        unsigned long long k2 = (unsigned long long)b2;
        const int s0 = (int)(k0 & 1023ull);
        const int s1 = (int)(k1 & 1023ull);
        const int s2 = (int)(k2 & 1023ull);
        float d0 = __uint_as_float((unsigned int)(k0 >> 10));
        float d1 = __uint_as_float((unsigned int)(k1 >> 10));
        float d2 = __uint_as_float((unsigned int)(k2 >> 10));
        float w0 = 1.f / fmaxf(d0, 1e-16f);
        float w1 = 1.f / fmaxf(d1, 1e-16f);
        float w2 = 1.f / fmaxf(d2, 1e-16f);
        float inv = 1.f / (w0 + w1 + w2);
        idx_out[q * 3 + 0] = cloud * NS + s0;
        idx_out[q * 3 + 1] = cloud * NS + s1;
        idx_out[q * 3 + 2] = cloud * NS + s2;
        wgt_out[q * 3 + 0] = w0 * inv;
        wgt_out[q * 3 + 1] = w1 * inv;
        wgt_out[q * 3 + 2] = w2 * inv;
    }
}

// ---- prep: W1/W2 swizzle into MFMA B-fragment order + out tail section ----
// Wf layout: Wf[kblk][n(16)][lane(64)][8]
//   k = kblk*32 + (lane>>4)*8 + j ; col = n*16 + (lane&15)
#define PREP_B1 (K1 * HD / 256)         // 320 blocks for W1f
#define PREP_B2 (HD * HD / 256)         // 256 blocks for W2f
#define PREP_B3 ((MTOT * 3) / 256)      // 768 blocks for tail
__global__ __launch_bounds__(256) void prep_kernel(
    const float* __restrict__ W1, const float* __restrict__ W2,
    const float* __restrict__ pos_skip,
    unsigned short* __restrict__ W1f, unsigned short* __restrict__ W2f,
    float* __restrict__ out)
{
    const int b = blockIdx.x;
    if (b < PREP_B1 + PREP_B2) {
        const bool is1 = b < PREP_B1;
        const int id = (is1 ? b : b - PREP_B1) * 256 + threadIdx.x;
        const int j    = id & 7;
        const int lane = (id >> 3) & 63;
        const int n    = (id >> 9) & 15;
        const int kblk = id >> 13;
        const int k   = kblk * 32 + (lane >> 4) * 8 + j;
        const int col = n * 16 + (lane & 15);
        if (is1) W1f[id] = f2bf(W1[(size_t)k * HD + col]);
        else     W2f[id] = f2bf(W2[(size_t)k * HD + col]);
    } else {
        const int i = (b - PREP_B1 - PREP_B2) * 256 + threadIdx.x;
        const size_t o1 = (size_t)MTOT * HD;
        out[o1 + i] = pos_skip[i];                                  // i < MTOT*3
        if (i < MTOT) out[o1 + (size_t)MTOT * 3 + i] = (float)(i >> 12);
    }
}

// ------- fused GEMM1: h1 = relu([interp(x) | x_skip] @ W1 + b1), bf16 out -------
// Block tile 64M x 256N, 4 waves each 64M x 64N. A-tile built on the fly:
// thread t owns row t>>2, 8-col segment t&3; gathers 3 x-rows (L2-resident),
// blends with per-row weights, converts bf16, ds_writes into padded LDS tile.
// kb>=8 sources x_skip (wave-uniform branch). B staged via gll16 (dbuf).
#define APAD 40   // LDS A row stride in halves (80 B: non-pow2 -> ~2-way banks)
__global__ __launch_bounds__(256, 3) void gemm1_fused_kernel(
    const float* __restrict__ x, const float* __restrict__ x_skip,
    const int* __restrict__ idx, const float* __restrict__ wgt,
    const unsigned short* __restrict__ Wf, const float* __restrict__ bias,
    unsigned short* __restrict__ outb)
{
    constexpr int NKB = K1 / 32;        // 10
    __shared__ __align__(16) unsigned short ldsB[2][16 * 512]; // 32 KB
    __shared__ __align__(16) unsigned short ldsA[2][64 * APAD]; // 10 KB

    const int tid = threadIdx.x;
    const int w = tid >> 6, lane = tid & 63;
    const int l15 = lane & 15, lk = lane >> 4;
    const int bm = blockIdx.x;

    // per-thread A-staging role (fixed across k-steps)
    const int arow_ = tid >> 2;          // 0..63
    const int aseg  = tid & 3;           // 8-col segment within k-step
    const int rg    = bm * 64 + arow_;   // global row
    const int i0 = idx[rg * 3 + 0], i1 = idx[rg * 3 + 1], i2 = idx[rg * 3 + 2];
    const float w0 = wgt[rg * 3 + 0], w1 = wgt[rg * 3 + 1], w2 = wgt[rg * 3 + 2];

    // B staging: wave w stages n-frags {4w..4w+3}
    const unsigned short* wsrc = Wf + w * 2048 + lane * 8;
    unsigned short* ldB0 = &ldsB[0][w * 2048];
    unsigned short* ldB1 = &ldsB[1][w * 2048];

    auto stageA = [&](int kb, int buf) {
        f32x4 r0, r1;
        const int c = kb * 32 + aseg * 8;
        if (kb < 8) {
            const float* p0 = x + (size_t)i0 * CIN + c;
            const float* p1 = x + (size_t)i1 * CIN + c;
            const float* p2 = x + (size_t)i2 * CIN + c;
            f32x4 a0 = *(const f32x4*)p0, a1 = *(const f32x4*)(p0 + 4);
            f32x4 b0 = *(const f32x4*)p1, b1 = *(const f32x4*)(p1 + 4);
            f32x4 c0 = *(const f32x4*)p2, c1 = *(const f32x4*)(p2 + 4);
            r0 = a0 * w0 + b0 * w1 + c0 * w2;
            r1 = a1 * w0 + b1 * w1 + c1 * w2;
        } else {
            const float* ps = x_skip + (size_t)rg * CSK + (c - 256);
            r0 = *(const f32x4*)ps;
            r1 = *(const f32x4*)(ps + 4);
        }
        bf16x8 o;
        o[0] = (__bf16)r0[0]; o[1] = (__bf16)r0[1];
        o[2] = (__bf16)r0[2]; o[3] = (__bf16)r0[3];
        o[4] = (__bf16)r1[0]; o[5] = (__bf16)r1[1];
        o[6] = (__bf16)r1[2]; o[7] = (__bf16)r1[3];
        *(bf16x8*)&ldsA[buf][arow_ * APAD + aseg * 8] = o;
    };
    auto stageB = [&](int kb, unsigned short* d) {
        const unsigned short* s = wsrc + (size_t)kb * 8192;
        gll16(s,        d);
        gll16(s + 512,  d + 512);
        gll16(s + 1024, d + 1024);
        gll16(s + 1536, d + 1536);
    };

    stageA(0, 0);
    stageB(0, ldB0);

    f32x4 acc[4][4];
    #pragma unroll
    for (int mf = 0; mf < 4; ++mf)
        #pragma unroll
        for (int nf = 0; nf < 4; ++nf)
            acc[mf][nf] = f32x4{0.f, 0.f, 0.f, 0.f};

    for (int kb = 0; kb < NKB; ++kb) {
        __syncthreads();   // buf[kb&1] staged (vmcnt drained at barrier); buf[!cur] reads done
        if (kb + 1 < NKB) {
            stageA(kb + 1, (kb + 1) & 1);
            stageB(kb + 1, (kb & 1) ? ldB0 : ldB1);
        }
        bf16x8 a[4], b[4];
        #pragma unroll
        for (int mf = 0; mf < 4; ++mf)
            a[mf] = *(const bf16x8*)&ldsA[kb & 1][(mf * 16 + l15) * APAD + lk * 8];
        #pragma unroll
        for (int nf = 0; nf < 4; ++nf)
            b[nf] = *(const bf16x8*)&ldsB[kb & 1][(w * 4 + nf) * 512 + lane * 8];
        #pragma unroll
        for (int mf = 0; mf < 4; ++mf)
            #pragma unroll
            for (int nf = 0; nf < 4; ++nf)
                acc[mf][nf] = __builtin_amdgcn_mfma_f32_16x16x32_bf16(
                    a[mf], b[nf], acc[mf][nf], 0, 0, 0);
    }

    // epilogue: col = lane&15 (+16*nf), row = lk*4 + r (+16*mf)
    const int rbase = bm * 64 + lk * 4;
    const int cbase = w * 64 + l15;
    #pragma unroll
    for (int nf = 0; nf < 4; ++nf) {
        const int col = cbase + nf * 16;
        const float bv = bias[col];
        #pragma unroll
        for (int mf = 0; mf < 4; ++mf) {
            #pragma unroll
            for (int r = 0; r < 4; ++r) {
                float v = fmaxf(acc[mf][nf][r] + bv, 0.f);
                outb[(size_t)(rbase + mf * 16 + r) * HD + col] = f2bf(v);
            }
        }
    }
}

// ---------------- GEMM2: out[M,256] = relu(h1[M,256] @ W2 + b2), f32 ----------------
// Block tile 128M x 128N, 4 waves at 64x64 each (proven round-4 structure).
__global__ __launch_bounds__(256, 3) void gemm2_kernel(
    const unsigned short* __restrict__ A, const unsigned short* __restrict__ Wf,
    const float* __restrict__ bias, float* __restrict__ outf)
{
    constexpr int NKB = HD / 32;        // 8
    __shared__ __align__(16) unsigned short ldsB[2][8 * 512];

    const int tid = threadIdx.x;
    const int w = tid >> 6, lane = tid & 63;
    const int wm = w >> 1, wn = w & 1;
    const int l15 = lane & 15, lk = lane >> 4;
    const int bm = blockIdx.x >> 1, bn = blockIdx.x & 1;

    const unsigned short* wsrc = Wf + bn * 4096 + w * 1024 + lane * 8;
    unsigned short* ld0 = &ldsB[0][w * 1024];
    unsigned short* ld1 = &ldsB[1][w * 1024];

    gll16(wsrc,       ld0);
    gll16(wsrc + 512, ld0 + 512);

    const unsigned short* arow = A + (size_t)(bm * 128 + wm * 64 + l15) * HD + lk * 8;

    f32x4 acc[4][4];
    #pragma unroll
    for (int mf = 0; mf < 4; ++mf)
        #pragma unroll
        for (int nf = 0; nf < 4; ++nf)
            acc[mf][nf] = f32x4{0.f, 0.f, 0.f, 0.f};

    for (int kb = 0; kb < NKB; ++kb) {
        __syncthreads();
        if (kb + 1 < NKB) {
            const unsigned short* s = wsrc + (size_t)(kb + 1) * 8192;
            unsigned short* d = (kb & 1) ? ld0 : ld1;
            gll16(s,       d);
            gll16(s + 512, d + 512);
        }
        bf16x8 a[4], b[4];
        #pragma unroll
        for (int mf = 0; mf < 4; ++mf)
            a[mf] = *(const bf16x8*)(arow + (size_t)mf * 16 * HD + kb * 32);
        #pragma unroll
        for (int nf = 0; nf < 4; ++nf)
            b[nf] = *(const bf16x8*)(&ldsB[kb & 1][(wn * 4 + nf) * 512 + lane * 8]);
        #pragma unroll
        for (int mf = 0; mf < 4; ++mf)
            #pragma unroll
            for (int nf = 0; nf < 4; ++nf)
                acc[mf][nf] = __builtin_amdgcn_mfma_f32_16x16x32_bf16(
                    a[mf], b[nf], acc[mf][nf], 0, 0, 0);
    }

    const int rbase = bm * 128 + wm * 64 + lk * 4;
    const int cbase = bn * 128 + wn * 64 + l15;
    #pragma unroll
    for (int nf = 0; nf < 4; ++nf) {
        const int col = cbase + nf * 16;
        const float bv = bias[col];
        #pragma unroll
        for (int mf = 0; mf < 4; ++mf) {
            #pragma unroll
            for (int r = 0; r < 4; ++r) {
                float v = fmaxf(acc[mf][nf][r] + bv, 0.f);
                outf[(size_t)(rbase + mf * 16 + r) * HD + col] = v;
            }
        }
    }
}

extern "C" void kernel_launch(void* const* d_in, const int* in_sizes, int n_in,
                              void* d_out, int out_size, void* d_ws, size_t ws_size,
                              hipStream_t stream)
{
    const float* x        = (const float*)d_in[0];
    const float* pos      = (const float*)d_in[1];
    const float* x_skip   = (const float*)d_in[2];
    const float* pos_skip = (const float*)d_in[3];
    const float* W1       = (const float*)d_in[4];
    const float* b1       = (const float*)d_in[5];
    const float* W2       = (const float*)d_in[6];
    const float* b2       = (const float*)d_in[7];
    float* out = (float*)d_out;

    char* ws = (char*)d_ws;
    int*            idxb = (int*)(ws + IDX_OFF);
    float*          wgtb = (float*)(ws + WGT_OFF);
    unsigned short* W1f  = (unsigned short*)(ws + W1F_OFF);
    unsigned short* W2f  = (unsigned short*)(ws + W2F_OFF);
    unsigned short* h1   = (unsigned short*)(ws + H1_OFF);

    knn_kernel<<<BB * (NT / KNN_QPB), 256, 0, stream>>>(pos, pos_skip, idxb, wgtb);
    prep_kernel<<<PREP_B1 + PREP_B2 + PREP_B3, 256, 0, stream>>>(
        W1, W2, pos_skip, W1f, W2f, out);
    gemm1_fused_kernel<<<MTOT / 64, 256, 0, stream>>>(
        x, x_skip, idxb, wgtb, W1f, b1, h1);
    gemm2_kernel<<<(MTOT / 128) * 2, 256, 0, stream>>>(h1, W2f, b2, out);
}

// Round 7
// 96.241 us; speedup vs baseline: 3.0787x; 1.0734x over previous
//
#include <hip/hip_runtime.h>
#include <hip/hip_bf16.h>

// Problem constants (from reference)
#define BB   16
#define NS   1024
#define NT   4096
#define CIN  256
#define CSK  64
#define HD   256           // hidden dim / output cols
#define K1   (CIN + CSK)   // 320
#define MTOT (BB * NT)     // 65536

typedef __attribute__((ext_vector_type(4))) float f32x4;
typedef __attribute__((ext_vector_type(8))) __bf16 bf16x8;
typedef __attribute__((ext_vector_type(4))) unsigned short ushort4v;

// ws layout (bytes)
#define IDX_OFF 0u                    // int[MTOT*3]      = 786432
#define WGT_OFF 786432u               // float[MTOT*3]    = 786432
#define W1F_OFF 1572864u              // bf16[320*256]    = 163840
#define W2F_OFF 1736704u              // bf16[256*256]    = 131072
#define H1_OFF  2097152u              // bf16[MTOT*256]   = 33554432

static __device__ __forceinline__ unsigned short f2bf(float f) {
    union { float f; unsigned int u; } v; v.f = f;
    unsigned int r = (v.u + 0x7FFFu + ((v.u >> 16) & 1u)) >> 16;
    return (unsigned short)r;
}

// async global->LDS, 16 B per lane; dest = wave-uniform base (+ lane*16 by HW)
static __device__ __forceinline__ void gll16(const unsigned short* g, unsigned short* l) {
    __builtin_amdgcn_global_load_lds(
        (const __attribute__((address_space(1))) unsigned int*)g,
        (__attribute__((address_space(3))) unsigned int*)l,
        16, 0, 0);
}

// ---------------- kNN (K=3) over per-cloud 1024 points ----------------
// 8 lanes per query. Exact lex key packed in an integer-valued DOUBLE:
//   key = (double)f32bits(d) * 1024 + s    (< 2^41, exact in f64)
// monotone in d (d >= 0), ties -> lowest s (matches lax.top_k).
#define KNN_P   8
#define KNN_QPB (256 / KNN_P)     // 32 queries per block
__global__ __launch_bounds__(256) void knn_kernel(
    const float* __restrict__ pos, const float* __restrict__ pos_skip,
    int* __restrict__ idx_out, float* __restrict__ wgt_out)
{
    __shared__ float4 sp[NS];
    const int blocks_per_cloud = NT / KNN_QPB;          // 128
    const int cloud = blockIdx.x / blocks_per_cloud;
    const int q = cloud * NT + (blockIdx.x % blocks_per_cloud) * KNN_QPB
                + (threadIdx.x >> 3);
    const int p = threadIdx.x & (KNN_P - 1);
    const float* pc = pos + (size_t)cloud * NS * 3;
    for (int i = threadIdx.x; i < NS; i += 256) {
        sp[i] = make_float4(pc[i * 3 + 0], pc[i * 3 + 1], pc[i * 3 + 2], 0.f);
    }
    __syncthreads();

    const float qx = pos_skip[q * 3 + 0];
    const float qy = pos_skip[q * 3 + 1];
    const float qz = pos_skip[q * 3 + 2];

    double b0 = 1e300, b1 = 1e300, b2 = 1e300;
    double si = (double)p;
    #pragma unroll 4
    for (int i = 0; i < NS / KNN_P; ++i) {
        const int s = i * KNN_P + p;
        float4 c = sp[s];
        float dx = qx - c.x, dy = qy - c.y, dz = qz - c.z;
        float d = dx * dx + dy * dy + dz * dz;
        double key = fma((double)__float_as_uint(d), 1024.0, si);
        si += (double)KNN_P;
        double t0 = fmin(b0, key), m0 = fmax(b0, key); b0 = t0;
        double t1 = fmin(b1, m0),  m1 = fmax(b1, m0);  b1 = t1;
        b2 = fmin(b2, m1);
    }
    #pragma unroll
    for (int m = 1; m <= 4; m <<= 1) {
        double o0 = __shfl_xor(b0, m, 64);
        double o1 = __shfl_xor(b1, m, 64);
        double o2 = __shfl_xor(b2, m, 64);
        double t0, m0, t1, m1;
        t0 = fmin(b0, o0); m0 = fmax(b0, o0); b0 = t0;
        t1 = fmin(b1, m0); m1 = fmax(b1, m0); b1 = t1;
        b2 = fmin(b2, m1);
        t0 = fmin(b0, o1); m0 = fmax(b0, o1); b0 = t0;
        t1 = fmin(b1, m0); m1 = fmax(b1, m0); b1 = t1;
        b2 = fmin(b2, m1);
        t0 = fmin(b0, o2); m0 = fmax(b0, o2); b0 = t0;
        t1 = fmin(b1, m0); m1 = fmax(b1, m0); b1 = t1;
        b2 = fmin(b2, m1);
    }
    if (p == 0) {
        unsigned long long k0 = (unsigned long long)b0;
        unsigned long long k1 = (unsigned long long)b1;
        unsigned long long k2 = (unsigned long long)b2;
        const int s0 = (int)(k0 & 1023ull);
        const int s1 = (int)(k1 & 1023ull);
        const int s2 = (int)(k2 & 1023ull);
        float d0 = __uint_as_float((unsigned int)(k0 >> 10));
        float d1 = __uint_as_float((unsigned int)(k1 >> 10));
        float d2 = __uint_as_float((unsigned int)(k2 >> 10));
        float w0 = 1.f / fmaxf(d0, 1e-16f);
        float w1 = 1.f / fmaxf(d1, 1e-16f);
        float w2 = 1.f / fmaxf(d2, 1e-16f);
        float inv = 1.f / (w0 + w1 + w2);
        idx_out[q * 3 + 0] = cloud * NS + s0;
        idx_out[q * 3 + 1] = cloud * NS + s1;
        idx_out[q * 3 + 2] = cloud * NS + s2;
        wgt_out[q * 3 + 0] = w0 * inv;
        wgt_out[q * 3 + 1] = w1 * inv;
        wgt_out[q * 3 + 2] = w2 * inv;
    }
}

// ---- prep: W1/W2 swizzle into MFMA B-fragment order + out tail section ----
// Wf layout: Wf[kblk][n(16)][lane(64)][8]
//   k = kblk*32 + (lane>>4)*8 + j ; col = n*16 + (lane&15)
#define PREP_B1 (K1 * HD / 256)         // 320 blocks for W1f
#define PREP_B2 (HD * HD / 256)         // 256 blocks for W2f
#define PREP_B3 ((MTOT * 3) / 256)      // 768 blocks for tail
__global__ __launch_bounds__(256) void prep_kernel(
    const float* __restrict__ W1, const float* __restrict__ W2,
    const float* __restrict__ pos_skip,
    unsigned short* __restrict__ W1f, unsigned short* __restrict__ W2f,
    float* __restrict__ out)
{
    const int b = blockIdx.x;
    if (b < PREP_B1 + PREP_B2) {
        const bool is1 = b < PREP_B1;
        const int id = (is1 ? b : b - PREP_B1) * 256 + threadIdx.x;
        const int j    = id & 7;
        const int lane = (id >> 3) & 63;
        const int n    = (id >> 9) & 15;
        const int kblk = id >> 13;
        const int k   = kblk * 32 + (lane >> 4) * 8 + j;
        const int col = n * 16 + (lane & 15);
        if (is1) W1f[id] = f2bf(W1[(size_t)k * HD + col]);
        else     W2f[id] = f2bf(W2[(size_t)k * HD + col]);
    } else {
        const int i = (b - PREP_B1 - PREP_B2) * 256 + threadIdx.x;
        const size_t o1 = (size_t)MTOT * HD;
        out[o1 + i] = pos_skip[i];                                  // i < MTOT*3
        if (i < MTOT) out[o1 + (size_t)MTOT * 3 + i] = (float)(i >> 12);
    }
}

// ------- fused GEMM1: h1 = relu([interp(x) | x_skip] @ W1 + b1), bf16 out -------
// Block tile 64M x 256N, 4 waves each 64M x 64N. A-tile built on the fly.
// XCD-cloud affinity swizzle: dispatcher round-robins blockIdx across the 8
// XCDs (bid%8); remap so XCD x gets clouds {x, x+8} -> each XCD's gathers hit
// its own L2 (2MB x-slice < 4MB) instead of refilling all 8 L2s from L3/HBM.
#define APAD 40   // LDS A row stride in halves (80 B: non-pow2 -> ~2-way banks)
__global__ __launch_bounds__(256, 3) void gemm1_fused_kernel(
    const float* __restrict__ x, const float* __restrict__ x_skip,
    const int* __restrict__ idx, const float* __restrict__ wgt,
    const unsigned short* __restrict__ Wf, const float* __restrict__ bias,
    unsigned short* __restrict__ outb)
{
    constexpr int NKB = K1 / 32;        // 10
    __shared__ __align__(16) unsigned short ldsB[2][16 * 512]; // 32 KB
    __shared__ __align__(16) unsigned short ldsA[2][64 * APAD]; // 10 KB

    const int tid = threadIdx.x;
    const int w = tid >> 6, lane = tid & 63;
    const int l15 = lane & 15, lk = lane >> 4;

    // cloud<->XCD affinity (bijective on [0,1024))
    const int bid   = blockIdx.x;
    const int xcd   = bid & 7;
    const int j     = bid >> 3;                 // 0..127
    const int cloud = xcd + 8 * (j >> 6);       // 0..15
    const int bm    = cloud * 64 + (j & 63);    // row-block index

    // per-thread A-staging role (fixed across k-steps)
    const int arow_ = tid >> 2;          // 0..63
    const int aseg  = tid & 3;           // 8-col segment within k-step
    const int rg    = bm * 64 + arow_;   // global row
    const int i0 = idx[rg * 3 + 0], i1 = idx[rg * 3 + 1], i2 = idx[rg * 3 + 2];
    const float w0 = wgt[rg * 3 + 0], w1 = wgt[rg * 3 + 1], w2 = wgt[rg * 3 + 2];

    // B staging: wave w stages n-frags {4w..4w+3}
    const unsigned short* wsrc = Wf + w * 2048 + lane * 8;
    unsigned short* ldB0 = &ldsB[0][w * 2048];
    unsigned short* ldB1 = &ldsB[1][w * 2048];

    auto stageA = [&](int kb, int buf) {
        f32x4 r0, r1;
        const int c = kb * 32 + aseg * 8;
        if (kb < 8) {
            const float* p0 = x + (size_t)i0 * CIN + c;
            const float* p1 = x + (size_t)i1 * CIN + c;
            const float* p2 = x + (size_t)i2 * CIN + c;
            f32x4 a0 = *(const f32x4*)p0, a1 = *(const f32x4*)(p0 + 4);
            f32x4 b0 = *(const f32x4*)p1, b1 = *(const f32x4*)(p1 + 4);
            f32x4 c0 = *(const f32x4*)p2, c1 = *(const f32x4*)(p2 + 4);
            r0 = a0 * w0 + b0 * w1 + c0 * w2;
            r1 = a1 * w0 + b1 * w1 + c1 * w2;
        } else {
            const float* ps = x_skip + (size_t)rg * CSK + (c - 256);
            r0 = *(const f32x4*)ps;
            r1 = *(const f32x4*)(ps + 4);
        }
        bf16x8 o;
        o[0] = (__bf16)r0[0]; o[1] = (__bf16)r0[1];
        o[2] = (__bf16)r0[2]; o[3] = (__bf16)r0[3];
        o[4] = (__bf16)r1[0]; o[5] = (__bf16)r1[1];
        o[6] = (__bf16)r1[2]; o[7] = (__bf16)r1[3];
        *(bf16x8*)&ldsA[buf][arow_ * APAD + aseg * 8] = o;
    };
    auto stageB = [&](int kb, unsigned short* d) {
        const unsigned short* s = wsrc + (size_t)kb * 8192;
        gll16(s,        d);
        gll16(s + 512,  d + 512);
        gll16(s + 1024, d + 1024);
        gll16(s + 1536, d + 1536);
    };

    stageA(0, 0);
    stageB(0, ldB0);

    f32x4 acc[4][4];
    #pragma unroll
    for (int mf = 0; mf < 4; ++mf)
        #pragma unroll
        for (int nf = 0; nf < 4; ++nf)
            acc[mf][nf] = f32x4{0.f, 0.f, 0.f, 0.f};

    for (int kb = 0; kb < NKB; ++kb) {
        __syncthreads();   // buf[kb&1] staged; prior reads of buf[!cur] done
        if (kb + 1 < NKB) {
            stageA(kb + 1, (kb + 1) & 1);
            stageB(kb + 1, (kb & 1) ? ldB0 : ldB1);
        }
        bf16x8 a[4], b[4];
        #pragma unroll
        for (int mf = 0; mf < 4; ++mf)
            a[mf] = *(const bf16x8*)&ldsA[kb & 1][(mf * 16 + l15) * APAD + lk * 8];
        #pragma unroll
        for (int nf = 0; nf < 4; ++nf)
            b[nf] = *(const bf16x8*)&ldsB[kb & 1][(w * 4 + nf) * 512 + lane * 8];
        #pragma unroll
        for (int mf = 0; mf < 4; ++mf)
            #pragma unroll
            for (int nf = 0; nf < 4; ++nf)
                acc[mf][nf] = __builtin_amdgcn_mfma_f32_16x16x32_bf16(
                    a[mf], b[nf], acc[mf][nf], 0, 0, 0);
    }

    // epilogue: col = lane&15 (+16*nf), row = lk*4 + r (+16*mf)
    const int rbase = bm * 64 + lk * 4;
    const int cbase = w * 64 + l15;
    #pragma unroll
    for (int nf = 0; nf < 4; ++nf) {
        const int col = cbase + nf * 16;
        const float bv = bias[col];
        #pragma unroll
        for (int mf = 0; mf < 4; ++mf) {
            #pragma unroll
            for (int r = 0; r < 4; ++r) {
                float v = fmaxf(acc[mf][nf][r] + bv, 0.f);
                outb[(size_t)(rbase + mf * 16 + r) * HD + col] = f2bf(v);
            }
        }
    }
}

// ---------------- GEMM2: out[M,256] = relu(h1[M,256] @ W2 + b2), f32 ----------------
// Block tile 128M x 128N, 4 waves at 64x64 each (proven round-4 structure).
__global__ __launch_bounds__(256, 3) void gemm2_kernel(
    const unsigned short* __restrict__ A, const unsigned short* __restrict__ Wf,
    const float* __restrict__ bias, float* __restrict__ outf)
{
    constexpr int NKB = HD / 32;        // 8
    __shared__ __align__(16) unsigned short ldsB[2][8 * 512];

    const int tid = threadIdx.x;
    const int w = tid >> 6, lane = tid & 63;
    const int wm = w >> 1, wn = w & 1;
    const int l15 = lane & 15, lk = lane >> 4;
    const int bm = blockIdx.x >> 1, bn = blockIdx.x & 1;

    const unsigned short* wsrc = Wf + bn * 4096 + w * 1024 + lane * 8;
    unsigned short* ld0 = &ldsB[0][w * 1024];
    unsigned short* ld1 = &ldsB[1][w * 1024];

    gll16(wsrc,       ld0);
    gll16(wsrc + 512, ld0 + 512);

    const unsigned short* arow = A + (size_t)(bm * 128 + wm * 64 + l15) * HD + lk * 8;

    f32x4 acc[4][4];
    #pragma unroll
    for (int mf = 0; mf < 4; ++mf)
        #pragma unroll
        for (int nf = 0; nf < 4; ++nf)
            acc[mf][nf] = f32x4{0.f, 0.f, 0.f, 0.f};

    for (int kb = 0; kb < NKB; ++kb) {
        __syncthreads();
        if (kb + 1 < NKB) {
            const unsigned short* s = wsrc + (size_t)(kb + 1) * 8192;
            unsigned short* d = (kb & 1) ? ld0 : ld1;
            gll16(s,       d);
            gll16(s + 512, d + 512);
        }
        bf16x8 a[4], b[4];
        #pragma unroll
        for (int mf = 0; mf < 4; ++mf)
            a[mf] = *(const bf16x8*)(arow + (size_t)mf * 16 * HD + kb * 32);
        #pragma unroll
        for (int nf = 0; nf < 4; ++nf)
            b[nf] = *(const bf16x8*)(&ldsB[kb & 1][(wn * 4 + nf) * 512 + lane * 8]);
        #pragma unroll
        for (int mf = 0; mf < 4; ++mf)
            #pragma unroll
            for (int nf = 0; nf < 4; ++nf)
                acc[mf][nf] = __builtin_amdgcn_mfma_f32_16x16x32_bf16(
                    a[mf], b[nf], acc[mf][nf], 0, 0, 0);
    }

    const int rbase = bm * 128 + wm * 64 + lk * 4;
    const int cbase = bn * 128 + wn * 64 + l15;
    #pragma unroll
    for (int nf = 0; nf < 4; ++nf) {
        const int col = cbase + nf * 16;
        const float bv = bias[col];
        #pragma unroll
        for (int mf = 0; mf < 4; ++mf) {
            #pragma unroll
            for (int r = 0; r < 4; ++r) {
                float v = fmaxf(acc[mf][nf][r] + bv, 0.f);
                outf[(size_t)(rbase + mf * 16 + r) * HD + col] = v;
            }
        }
    }
}

extern "C" void kernel_launch(void* const* d_in, const int* in_sizes, int n_in,
                              void* d_out, int out_size, void* d_ws, size_t ws_size,
                              hipStream_t stream)
{
    const float* x        = (const float*)d_in[0];
    const float* pos      = (const float*)d_in[1];
    const float* x_skip   = (const float*)d_in[2];
    const float* pos_skip = (const float*)d_in[3];
    const float* W1       = (const float*)d_in[4];
    const float* b1       = (const float*)d_in[5];
    const float* W2       = (const float*)d_in[6];
    const float* b2       = (const float*)d_in[7];
    float* out = (float*)d_out;

    char* ws = (char*)d_ws;
    int*            idxb = (int*)(ws + IDX_OFF);
    float*          wgtb = (float*)(ws + WGT_OFF);
    unsigned short* W1f  = (unsigned short*)(ws + W1F_OFF);
    unsigned short* W2f  = (unsigned short*)(ws + W2F_OFF);
    unsigned short* h1   = (unsigned short*)(ws + H1_OFF);

    knn_kernel<<<BB * (NT / KNN_QPB), 256, 0, stream>>>(pos, pos_skip, idxb, wgtb);
    prep_kernel<<<PREP_B1 + PREP_B2 + PREP_B3, 256, 0, stream>>>(
        W1, W2, pos_skip, W1f, W2f, out);
    gemm1_fused_kernel<<<MTOT / 64, 256, 0, stream>>>(
        x, x_skip, idxb, wgtb, W1f, b1, h1);
    gemm2_kernel<<<(MTOT / 128) * 2, 256, 0, stream>>>(h1, W2f, b2, out);
}